// Round 15
// baseline (218.321 us; speedup 1.0000x reference)
//
#include <hip/hip_runtime.h>
#include <hip/hip_bf16.h>
#include <math.h>
#include <type_traits>

#define TSEQ 4096
#define CDIM 768
#define NH 12
#define HD 64

typedef float f32x4 __attribute__((ext_vector_type(4)));
typedef __bf16 bf16x8 __attribute__((ext_vector_type(8)));
typedef short s16x8 __attribute__((ext_vector_type(8)));
typedef uint u32x4 __attribute__((ext_vector_type(4)));

__device__ inline ushort f2bf(float f) {
  __hip_bfloat16 h = __float2bfloat16(f);
  return __builtin_bit_cast(ushort, h);
}

__device__ inline void async16(const void* g, void* l) {
  __builtin_amdgcn_global_load_lds(
      (__attribute__((address_space(1))) unsigned int*)(uintptr_t)g,
      (__attribute__((address_space(3))) unsigned int*)(uintptr_t)l, 16, 0, 0);
}

// v_exp_f32 computes 2^x; s_nop covers the TRANS->VALU hazard
__device__ inline float exp2_fast(float x) {
  float r;
  asm volatile("v_exp_f32 %0, %1\n\ts_nop 0" : "=v"(r) : "v"(x));
  return r;
}

// pack two f32 -> two bf16 in one u32 (lo = a, hi = b)
__device__ inline uint cvtpk(float a, float b) {
  uint r;
  asm volatile("v_cvt_pk_bf16_f32 %0, %1, %2" : "=v"(r) : "v"(a), "v"(b));
  return r;
}

// swizzled fragment read from a [64][64] bf16 tile with row-chunk XOR swizzle
__device__ inline bf16x8 frag_read(const ushort* base, int row, int kk, int lane) {
  const int byte = row * 128 + ((((kk * 4 + (lane >> 4)) ^ (row & 7))) << 4);
  return *(const bf16x8*)((const char*)base + byte);
}

// ---------------- prep bodies ---------------------------------------------
__device__ void wconv_body(const float* __restrict__ W, ushort* __restrict__ Wt,
                           int K, int N, int bx, int by)
{
  __shared__ float sm[32][33];
  const int n0 = bx * 32, k0 = by * 32;
  const int c = threadIdx.x & 31, r0 = threadIdx.x >> 5;
#pragma unroll
  for (int i = 0; i < 4; ++i) {
    const int r = r0 + i * 8;
    sm[r][c] = W[(size_t)(k0 + r) * N + n0 + c];
  }
  __syncthreads();
#pragma unroll
  for (int i = 0; i < 4; ++i) {
    const int r = r0 + i * 8;
    Wt[(size_t)(n0 + r) * K + k0 + c] = f2bf(sm[c][r]);
  }
}

__device__ void ln_body(const float* __restrict__ x, const float* __restrict__ w,
                        const float* __restrict__ b, ushort* __restrict__ out, int row)
{
  const int tid = threadIdx.x;
  const float* xr = x + (size_t)row * CDIM;
  float v[3];
  float s1 = 0.f, s2 = 0.f;
#pragma unroll
  for (int i = 0; i < 3; ++i) {
    v[i] = xr[tid + i * 256];
    s1 += v[i];
    s2 += v[i] * v[i];
  }
#pragma unroll
  for (int off = 32; off >= 1; off >>= 1) {
    s1 += __shfl_xor(s1, off, 64);
    s2 += __shfl_xor(s2, off, 64);
  }
  __shared__ float red1[4], red2[4];
  if ((tid & 63) == 0) { red1[tid >> 6] = s1; red2[tid >> 6] = s2; }
  __syncthreads();
  s1 = red1[0] + red1[1] + red1[2] + red1[3];
  s2 = red2[0] + red2[1] + red2[2] + red2[3];
  const float mu = s1 * (1.f / CDIM);
  const float var = s2 * (1.f / CDIM) - mu * mu;
  const float inv = rsqrtf(var + 1e-5f);
#pragma unroll
  for (int i = 0; i < 3; ++i) {
    const int c2 = tid + i * 256;
    out[(size_t)row * CDIM + c2] = f2bf((v[i] - mu) * inv * w[c2] + b[c2]);
  }
}

// fused: 4x weight transpose + LN1 + zero-init of split-K accumulators
__global__ __launch_bounds__(256) void prep_kernel(
    const float* __restrict__ W_attn, ushort* __restrict__ Wt_attn,
    const float* __restrict__ W_proj, ushort* __restrict__ Wt_proj,
    const float* __restrict__ W_fc,   ushort* __restrict__ Wt_fc,
    const float* __restrict__ W_fc2,  ushort* __restrict__ Wt_fc2,
    const float* __restrict__ x, const float* __restrict__ ln1w,
    const float* __restrict__ ln1b, ushort* __restrict__ t_ln,
    float* __restrict__ zero1, float* __restrict__ zero2)
{
  int b = blockIdx.x;
  if (b < 1728) { wconv_body(W_attn, Wt_attn, 768, 2304, b % 72, b / 72); return; }
  b -= 1728;
  if (b < 576)  { wconv_body(W_proj, Wt_proj, 768, 768, b % 24, b / 24); return; }
  b -= 576;
  if (b < 2304) { wconv_body(W_fc, Wt_fc, 768, 3072, b % 96, b / 96); return; }
  b -= 2304;
  if (b < 2304) { wconv_body(W_fc2, Wt_fc2, 3072, 768, b % 24, b / 24); return; }
  b -= 2304;
  if (b < 4096) { ln_body(x, ln1w, ln1b, t_ln, b); return; }
  b -= 4096;
  // zero 12.58 MB each: 768 blocks x 256 thr x 4 iters x f32x4
  float* dst = (b < 768) ? zero1 : zero2;
  const int bb = (b < 768) ? b : b - 768;
  const f32x4 z = {0.f, 0.f, 0.f, 0.f};
#pragma unroll
  for (int i = 0; i < 4; ++i)
    *(f32x4*)&dst[((size_t)bb * 1024 + i * 256 + threadIdx.x) * 4] = z;
}

// LN2 standalone
__global__ __launch_bounds__(256) void ln_kernel(
    const float* __restrict__ x, const float* __restrict__ w,
    const float* __restrict__ b, ushort* __restrict__ out)
{
  ln_body(x, w, b, out, blockIdx.x);
}

// ------- 128xBN bf16 MFMA GEMM, 3-stage pipeline (counted vmcnt) ---------
// EPI 0: bf16 out;  EPI 1: fp32 out = res + v;  EPI 2: bf16 out = gelu(v)
// EPI 3: split-K=2 -> atomicAdd fp32 (kh=0 contributes res+bias too);
//        grid = 2x blocks, K = K-half, Kstride = full row stride.
template <int EPI, int BN>
__global__ __launch_bounds__(256) void gemm_bt(
    const ushort* __restrict__ A, const ushort* __restrict__ Bt,
    const float* __restrict__ bias, const float* __restrict__ res,
    ushort* __restrict__ outb, float* __restrict__ outf,
    int M, int N, int K, int gx, int Kstride)
{
  constexpr int NW = BN / 32;
  __shared__ __align__(16) ushort As[3][128 * 32];
  __shared__ __align__(16) ushort Bs[3][BN * 32];
  const int tid = threadIdx.x;
  const int lane = tid & 63;
  const int wv = tid >> 6;
  const int nwg = (int)gridDim.x;
  const int bid = (int)blockIdx.x;
  int sw = (bid & 7) * (nwg >> 3) + (bid >> 3);
  int kh = 0;
  if (EPI == 3) {
    const int half = nwg >> 1;
    if (sw >= half) { kh = 1; sw -= half; }
  }
  const int rowBase = (sw / gx) * 128;
  const int colBase = (sw % gx) * BN;
  const int wr = (wv >> 1) * 64;
  const int wc = (wv & 1) * (BN / 2);
  const int koffK = kh * K;

  f32x4 acc[4][NW] = {};

  const int e0 = tid * 8;
  const int r0 = e0 >> 5, c0 = e0 & 31;
  const int e1 = (tid + 256) * 8;
  const int r1 = e1 >> 5, c1 = e1 & 31;

  const ushort* Ag0 = A + (size_t)(rowBase + r0) * Kstride + koffK + c0;
  const ushort* Ag1 = A + (size_t)(rowBase + r1) * Kstride + koffK + c1;
  const ushort* Bg0 = Bt + (size_t)(colBase + r0) * Kstride + koffK + c0;
  const ushort* Bg1 = Bt + (size_t)(colBase + r1) * Kstride + koffK + c1;

  auto stage = [&](int buf, int k0) {
    async16(Ag0 + k0, &As[buf][e0]);
    async16(Ag1 + k0, &As[buf][e1]);
    async16(Bg0 + k0, &Bs[buf][e0]);
    if (BN == 128) async16(Bg1 + k0, &Bs[buf][e1]);
  };

  const int nt = K / 32;
  stage(0, 0);
  stage(1, 32);
  int b0 = 0, b1 = 1, b2 = 2;
  for (int t = 0; t < nt; ++t) {
    if (t < nt - 1) {
      if (BN == 128) asm volatile("s_waitcnt vmcnt(4)" ::: "memory");
      else           asm volatile("s_waitcnt vmcnt(3)" ::: "memory");
    } else {
      asm volatile("s_waitcnt vmcnt(0)" ::: "memory");
    }
    __builtin_amdgcn_sched_barrier(0);
    __builtin_amdgcn_s_barrier();
    __builtin_amdgcn_sched_barrier(0);
    if (t + 2 < nt) stage(b2, t * 32 + 64);

    bf16x8 af[4], bfr[NW];
#pragma unroll
    for (int m = 0; m < 4; ++m)
      af[m] = *(const bf16x8*)&As[b0][(wr + m * 16 + (lane & 15)) * 32 + (lane >> 4) * 8];
#pragma unroll
    for (int n = 0; n < NW; ++n)
      bfr[n] = *(const bf16x8*)&Bs[b0][(wc + n * 16 + (lane & 15)) * 32 + (lane >> 4) * 8];
#pragma unroll
    for (int m = 0; m < 4; ++m)
#pragma unroll
      for (int n = 0; n < NW; ++n)
        acc[m][n] = __builtin_amdgcn_mfma_f32_16x16x32_bf16(af[m], bfr[n], acc[m][n], 0, 0, 0);
    const int tmp = b0; b0 = b1; b1 = b2; b2 = tmp;
  }

#pragma unroll
  for (int n = 0; n < NW; ++n) {
    const int gc = colBase + wc + n * 16 + (lane & 15);
    const float bv = bias[gc];
#pragma unroll
    for (int m = 0; m < 4; ++m) {
#pragma unroll
      for (int j = 0; j < 4; ++j) {
        const int gr = rowBase + wr + m * 16 + (lane >> 4) * 4 + j;
        const size_t idx = (size_t)gr * N + gc;
        const float v = acc[m][n][j];
        if (EPI == 0) {
          outb[idx] = f2bf(v + bv);
        } else if (EPI == 1) {
          outf[idx] = res[idx] + v + bv;
        } else if (EPI == 2) {
          const float vb = v + bv;
          const float g = 0.5f * vb * (1.0f + erff(vb * 0.70710678118654752f));
          outb[idx] = f2bf(g);
        } else {
          float add = v;
          if (kh == 0) add += bv + res[idx];
          atomicAdd(&outf[idx], add);
        }
      }
    }
  }
}

// ---------------- causal flash attention, 64x64 tiles, hd=64 -------------
// (round-9 verified version, 60.9 us, setprio restored)
__global__ __launch_bounds__(256) void attn_kernel(
    const ushort* __restrict__ qkv, ushort* __restrict__ att)
{
  __shared__ __align__(16) ushort Ks[2][64 * 64];
  __shared__ __align__(16) ushort Vt[2][64 * 64];   // V^T [d][col: kh*32+sigma]

  const int tid = threadIdx.x;
  const int lane = tid & 63;
  const int wv = tid >> 6;
  const int g = lane >> 4;
  const int ql = lane & 15;
  const int kh = wv & 1;          // key-half owned
  const int qh = wv >> 1;         // q-half owned
  // snake remap: CU's resident blocks {p, 511-p, 512+p} -> balanced work
  const int p_ = blockIdx.x & 255, grp = blockIdx.x >> 8;
  const int item = (grp & 1) ? (grp * 256 + 255 - p_) : (grp * 256 + p_);
  const int qb = 63 - (item / 12);
  const int h = item % 12;
  const int t0 = qb * 64;
  const size_t rs = 3 * CDIM;
  const int qo = h * HD, ko = CDIM + h * HD, vo = 2 * CDIM + h * HD;

  const float cexp = 0.18033688f;            // 0.125 * log2(e)
  const float cbias = -32.0f * 0.18033688f;  // fixed max M_raw = 32

  // K staging: pre-swizzled global source -> linear LDS dest
  const int L0 = tid * 16, L1 = (tid + 256) * 16;
  const int r_0 = L0 >> 7, c_0 = ((L0 >> 4) & 7) ^ (r_0 & 7);
  const int r_1 = L1 >> 7, c_1 = ((L1 >> 4) & 7) ^ (r_1 & 7);
  const ushort* kg0 = qkv + (size_t)r_0 * rs + ko + c_0 * 8;
  const ushort* kg1 = qkv + (size_t)r_1 * rs + ko + c_1 * 8;

  // V reg staging: keys (vt, vt+1) x d in [vd, vd+8)
  const int vt = (tid >> 3) * 2;
  const int vd = (tid & 7) * 8;
  const int s32 = vt & 31;
  const int col2 = (vt >> 5) * 64 + (8 * ((s32 >> 2) & 3) + 4 * (s32 >> 4) + (s32 & 3)) * 2;
  const ushort* vg = qkv + (size_t)vt * rs + vo + vd;

  // Q fragments: q rows 32qh + 16qg + ql, d-chunks kk
  bf16x8 qf[2][2];
#pragma unroll
  for (int qg = 0; qg < 2; ++qg) {
    const ushort* qrow = qkv + (size_t)(t0 + 32 * qh + 16 * qg + ql) * rs + qo + g * 8;
    qf[qg][0] = *(const bf16x8*)(qrow);
    qf[qg][1] = *(const bf16x8*)(qrow + 32);
  }

  // prologue: vr(0), K(0) -> LDS, pack-write V^T(0)
  s16x8 vA0 = *(const s16x8*)(vg);
  s16x8 vA1 = *(const s16x8*)(vg + rs);
  async16(kg0, (char*)Ks[0] + L0);
  async16(kg1, (char*)Ks[0] + L1);
#pragma unroll
  for (int jj = 0; jj < 8; ++jj) {      // compiler waits vr(0) here
    const int d = vd + jj;
    const uint val = (uint)(ushort)vA0[jj] | ((uint)(ushort)vA1[jj] << 16);
    *(uint*)((char*)Vt[0] + d * 128 + (col2 ^ (((d >> 1) & 7) << 4))) = val;
  }

  f32x4 accO[2][4] = {};
  f32x4 accL[2] = {};
  const bf16x8 ones = __builtin_bit_cast(bf16x8,
      (u32x4){0x3F803F80u, 0x3F803F80u, 0x3F803F80u, 0x3F803F80u});
  const int swzv = (ql >> 1) & 7;

  int cur = 0;
  auto body = [&](int kb, int curb, auto diag_c) {
    constexpr bool DIAG = decltype(diag_c)::value;
    const size_t koff = (size_t)(kb + 1) * 64 * rs;

    // issue vr(kb+1) before the wait (stays in flight across this body)
    if (!DIAG) {
      vA0 = *(const s16x8*)(vg + koff);
      vA1 = *(const s16x8*)(vg + koff + rs);
      asm volatile("s_waitcnt vmcnt(2) lgkmcnt(0)" ::: "memory");
    } else {
      asm volatile("s_waitcnt vmcnt(0) lgkmcnt(0)" ::: "memory");
    }
    __builtin_amdgcn_sched_barrier(0);
    __builtin_amdgcn_s_barrier();
    __builtin_amdgcn_sched_barrier(0);

    // stage K(kb+1) post-barrier (other buffer; readers of it passed barrier)
    if (!DIAG) {
      async16(kg0 + koff, (char*)Ks[curb ^ 1] + L0);
      async16(kg1 + koff, (char*)Ks[curb ^ 1] + L1);
    }

    // QK^T: D[key][q]; A = K rows (wave's 32), B = Q (wave's 32 rows, regs)
    f32x4 accS[2][2] = {};   // [kg][qg]
    __builtin_amdgcn_s_setprio(1);
#pragma unroll
    for (int kg = 0; kg < 2; ++kg)
#pragma unroll
      for (int kk = 0; kk < 2; ++kk) {
        const bf16x8 A = frag_read(Ks[curb], 32 * kh + 16 * kg + ql, kk, lane);
#pragma unroll
        for (int qg = 0; qg < 2; ++qg)
          accS[kg][qg] = __builtin_amdgcn_mfma_f32_16x16x32_bf16(
              A, qf[qg][kk], accS[kg][qg], 0, 0, 0);
      }
    __builtin_amdgcn_s_setprio(0);

    // p = 2^(s*c + cbias); mask only on peeled diag tile; pack in-reg
    bf16x8 pa[2];
#pragma unroll
    for (int qg = 0; qg < 2; ++qg) {
      float e[2][4];
#pragma unroll
      for (int kg = 0; kg < 2; ++kg)
#pragma unroll
        for (int j = 0; j < 4; ++j) {
          float s = exp2_fast(fmaf(accS[kg][qg][j], cexp, cbias));
          if (DIAG && (32 * kh + 16 * kg + 4 * g + j) > (32 * qh + 16 * qg + ql)) s = 0.f;
          e[kg][j] = s;
        }
      const uint w0 = cvtpk(e[0][0], e[0][1]);
      const uint w1 = cvtpk(e[0][2], e[0][3]);
      const uint w2 = cvtpk(e[1][0], e[1][1]);
      const uint w3 = cvtpk(e[1][2], e[1][3]);
      pa[qg] = __builtin_bit_cast(bf16x8, (u32x4){w0, w1, w2, w3});
    }

    // PV: D[q][d]; A = pa, B = Vt rows (d), wave's 32-key column slice.
    __builtin_amdgcn_s_setprio(1);
#pragma unroll
    for (int n = 0; n < 4; ++n) {
      const int byte = (16 * n + ql) * 128 + ((kh * 64 + 16 * g) ^ (swzv << 4));
      const bf16x8 bv = *(const bf16x8*)((const char*)Vt[curb] + byte);
#pragma unroll
      for (int qg = 0; qg < 2; ++qg)
        accO[qg][n] = __builtin_amdgcn_mfma_f32_16x16x32_bf16(pa[qg], bv, accO[qg][n], 0, 0, 0);
    }
#pragma unroll
    for (int qg = 0; qg < 2; ++qg)
      accL[qg] = __builtin_amdgcn_mfma_f32_16x16x32_bf16(pa[qg], ones, accL[qg], 0, 0, 0);
    __builtin_amdgcn_s_setprio(0);

    // pack-write V^T(kb+1)
    if (!DIAG) {
#pragma unroll
      for (int jj = 0; jj < 8; ++jj) {
        const int d = vd + jj;
        const uint val = (uint)(ushort)vA0[jj] | ((uint)(ushort)vA1[jj] << 16);
        *(uint*)((char*)Vt[curb ^ 1] + d * 128 + (col2 ^ (((d >> 1) & 7) << 4))) = val;
      }
    }
  };

  for (int kb = 0; kb < qb; ++kb) {
    body(kb, cur, std::false_type{});
    cur ^= 1;
  }
  body(qb, cur, std::true_type{});

  // -------- merge kh partials (fixed-max => exactly additive) ------------
  __syncthreads();                       // all PV reads of Vt/Ks done
  float* mO = (float*)&Ks[0][0];         // [qh][qg][n][lane] f32x4 = 16KB
  float* mL = (float*)&Vt[0][0];         // [qh][qg][lane] f32x4 = 4KB
  if (kh == 1) {
#pragma unroll
    for (int qg = 0; qg < 2; ++qg) {
#pragma unroll
      for (int n = 0; n < 4; ++n)
        *(f32x4*)&mO[(((qh * 2 + qg) * 4 + n) * 64 + lane) * 4] = accO[qg][n];
      *(f32x4*)&mL[((qh * 2 + qg) * 64 + lane) * 4] = accL[qg];
    }
  }
  __syncthreads();
  if (kh == 0) {
#pragma unroll
    for (int qg = 0; qg < 2; ++qg) {
      const f32x4 ls = accL[qg] + *(const f32x4*)&mL[((qh * 2 + qg) * 64 + lane) * 4];
      f32x4 inv4;
#pragma unroll
      for (int jr = 0; jr < 4; ++jr) inv4[jr] = 1.0f / ls[jr];
#pragma unroll
      for (int n = 0; n < 4; ++n) {
        const f32x4 o = accO[qg][n] +
            *(const f32x4*)&mO[(((qh * 2 + qg) * 4 + n) * 64 + lane) * 4];
#pragma unroll
        for (int jr = 0; jr < 4; ++jr) {
          const int tq = t0 + 32 * qh + 16 * qg + 4 * g + jr;
          const int d = 16 * n + ql;
          att[(size_t)tq * CDIM + h * HD + d] = f2bf(o[jr] * inv4[jr]);
        }
      }
    }
  }
}

// -------------------------------------------------------------------------
extern "C" void kernel_launch(void* const* d_in, const int* in_sizes, int n_in,
                              void* d_out, int out_size, void* d_ws, size_t ws_size,
                              hipStream_t stream)
{
  const float* x      = (const float*)d_in[0];
  const float* ln1_w  = (const float*)d_in[1];
  const float* ln1_b  = (const float*)d_in[2];
  const float* W_attn = (const float*)d_in[3];
  const float* b_attn = (const float*)d_in[4];
  const float* W_proj = (const float*)d_in[5];
  const float* b_proj = (const float*)d_in[6];
  const float* ln2_w  = (const float*)d_in[7];
  const float* ln2_b  = (const float*)d_in[8];
  const float* W_fc   = (const float*)d_in[9];
  const float* b_fc   = (const float*)d_in[10];
  const float* W_fc2  = (const float*)d_in[11];
  const float* b_fc2  = (const float*)d_in[12];
  float* out = (float*)d_out;

  char* base = (char*)d_ws;
  size_t off = 0;
  auto alloc = [&](size_t bytes) -> void* {
    void* q = base + off;
    off = (off + bytes + 255) & ~(size_t)255;
    return q;
  };
  ushort* Wt_attn = (ushort*)alloc(768ull * 2304 * 2);
  ushort* Wt_proj = (ushort*)alloc(768ull * 768 * 2);
  ushort* Wt_fc   = (ushort*)alloc(768ull * 3072 * 2);
  ushort* Wt_fc2  = (ushort*)alloc(3072ull * 768 * 2);
  ushort* t_ln    = (ushort*)alloc(4096ull * 768 * 2);
  ushort* t_att   = (ushort*)alloc(4096ull * 768 * 2);
  float*  t_x1    = (float*) alloc(4096ull * 768 * 4);
  ushort* t_big   = (ushort*)alloc(4096ull * 3072 * 2);
  ushort* t_qkv = t_big;     // qkv row-major (2304 cols)
  ushort* t_h   = t_big;     // FC hidden (after attn done with qkv)

  prep_kernel<<<12544, 256, 0, stream>>>(
      W_attn, Wt_attn, W_proj, Wt_proj, W_fc, Wt_fc, W_fc2, Wt_fc2,
      x, ln1_w, ln1_b, t_ln, out, t_x1);
  gemm_bt<0, 128><<<18 * 32, 256, 0, stream>>>(
      t_ln, Wt_attn, b_attn, nullptr, t_qkv, nullptr, 4096, 2304, 768, 18, 768);
  attn_kernel<<<dim3(768), 256, 0, stream>>>(t_qkv, t_att);
  // proj + residual, split-K=2 -> atomicAdd into zero-init'd t_x1
  gemm_bt<3, 64><<<2 * 12 * 32, 256, 0, stream>>>(
      t_att, Wt_proj, b_proj, x, nullptr, t_x1, 4096, 768, 384, 12, 768);
  ln_kernel<<<4096, 256, 0, stream>>>(t_x1, ln2_w, ln2_b, t_ln);
  gemm_bt<2, 128><<<24 * 32, 256, 0, stream>>>(
      t_ln, Wt_fc, b_fc, nullptr, t_h, nullptr, 4096, 3072, 768, 24, 768);
  // FC2 + residual, split-K=2 -> atomicAdd into zero-init'd out
  gemm_bt<3, 64><<<2 * 12 * 32, 256, 0, stream>>>(
      t_h, Wt_fc2, b_fc2, t_x1, nullptr, out, 4096, 768, 1536, 12, 3072);
}

// Round 16
// 186.180 us; speedup vs baseline: 1.1726x; 1.1726x over previous
//
#include <hip/hip_runtime.h>
#include <hip/hip_bf16.h>
#include <math.h>
#include <type_traits>

#define TSEQ 4096
#define CDIM 768
#define NH 12
#define HD 64

typedef float f32x4 __attribute__((ext_vector_type(4)));
typedef __bf16 bf16x8 __attribute__((ext_vector_type(8)));
typedef short s16x8 __attribute__((ext_vector_type(8)));
typedef uint u32x4 __attribute__((ext_vector_type(4)));

__device__ inline ushort f2bf(float f) {
  __hip_bfloat16 h = __float2bfloat16(f);
  return __builtin_bit_cast(ushort, h);
}

__device__ inline void async16(const void* g, void* l) {
  __builtin_amdgcn_global_load_lds(
      (__attribute__((address_space(1))) unsigned int*)(uintptr_t)g,
      (__attribute__((address_space(3))) unsigned int*)(uintptr_t)l, 16, 0, 0);
}

// v_exp_f32 computes 2^x; s_nop covers the TRANS->VALU hazard
__device__ inline float exp2_fast(float x) {
  float r;
  asm volatile("v_exp_f32 %0, %1\n\ts_nop 0" : "=v"(r) : "v"(x));
  return r;
}

// pack two f32 -> two bf16 in one u32 (lo = a, hi = b)
__device__ inline uint cvtpk(float a, float b) {
  uint r;
  asm volatile("v_cvt_pk_bf16_f32 %0, %1, %2" : "=v"(r) : "v"(a), "v"(b));
  return r;
}

// swizzled fragment read from a [64][64] bf16 tile with row-chunk XOR swizzle
__device__ inline bf16x8 frag_read(const ushort* base, int row, int kk, int lane) {
  const int byte = row * 128 + ((((kk * 4 + (lane >> 4)) ^ (row & 7))) << 4);
  return *(const bf16x8*)((const char*)base + byte);
}

// ---------------- prep bodies ---------------------------------------------
__device__ void wconv_body(const float* __restrict__ W, ushort* __restrict__ Wt,
                           int K, int N, int bx, int by)
{
  __shared__ float sm[32][33];
  const int n0 = bx * 32, k0 = by * 32;
  const int c = threadIdx.x & 31, r0 = threadIdx.x >> 5;
#pragma unroll
  for (int i = 0; i < 4; ++i) {
    const int r = r0 + i * 8;
    sm[r][c] = W[(size_t)(k0 + r) * N + n0 + c];
  }
  __syncthreads();
#pragma unroll
  for (int i = 0; i < 4; ++i) {
    const int r = r0 + i * 8;
    Wt[(size_t)(n0 + r) * K + k0 + c] = f2bf(sm[c][r]);
  }
}

__device__ void ln_body(const float* __restrict__ x, const float* __restrict__ w,
                        const float* __restrict__ b, ushort* __restrict__ out, int row)
{
  const int tid = threadIdx.x;
  const float* xr = x + (size_t)row * CDIM;
  float v[3];
  float s1 = 0.f, s2 = 0.f;
#pragma unroll
  for (int i = 0; i < 3; ++i) {
    v[i] = xr[tid + i * 256];
    s1 += v[i];
    s2 += v[i] * v[i];
  }
#pragma unroll
  for (int off = 32; off >= 1; off >>= 1) {
    s1 += __shfl_xor(s1, off, 64);
    s2 += __shfl_xor(s2, off, 64);
  }
  __shared__ float red1[4], red2[4];
  if ((tid & 63) == 0) { red1[tid >> 6] = s1; red2[tid >> 6] = s2; }
  __syncthreads();
  s1 = red1[0] + red1[1] + red1[2] + red1[3];
  s2 = red2[0] + red2[1] + red2[2] + red2[3];
  const float mu = s1 * (1.f / CDIM);
  const float var = s2 * (1.f / CDIM) - mu * mu;
  const float inv = rsqrtf(var + 1e-5f);
#pragma unroll
  for (int i = 0; i < 3; ++i) {
    const int c2 = tid + i * 256;
    out[(size_t)row * CDIM + c2] = f2bf((v[i] - mu) * inv * w[c2] + b[c2]);
  }
}

// fused: 4x weight transpose + LN1
__global__ __launch_bounds__(256) void prep_kernel(
    const float* __restrict__ W_attn, ushort* __restrict__ Wt_attn,
    const float* __restrict__ W_proj, ushort* __restrict__ Wt_proj,
    const float* __restrict__ W_fc,   ushort* __restrict__ Wt_fc,
    const float* __restrict__ W_fc2,  ushort* __restrict__ Wt_fc2,
    const float* __restrict__ x, const float* __restrict__ ln1w,
    const float* __restrict__ ln1b, ushort* __restrict__ t_ln)
{
  int b = blockIdx.x;
  if (b < 1728) { wconv_body(W_attn, Wt_attn, 768, 2304, b % 72, b / 72); return; }
  b -= 1728;
  if (b < 576)  { wconv_body(W_proj, Wt_proj, 768, 768, b % 24, b / 24); return; }
  b -= 576;
  if (b < 2304) { wconv_body(W_fc, Wt_fc, 768, 3072, b % 96, b / 96); return; }
  b -= 2304;
  if (b < 2304) { wconv_body(W_fc2, Wt_fc2, 3072, 768, b % 24, b / 24); return; }
  b -= 2304;
  ln_body(x, ln1w, ln1b, t_ln, b);
}

// LN2 standalone
__global__ __launch_bounds__(256) void ln_kernel(
    const float* __restrict__ x, const float* __restrict__ w,
    const float* __restrict__ b, ushort* __restrict__ out)
{
  ln_body(x, w, b, out, blockIdx.x);
}

// ------- 128xBN bf16 MFMA GEMM, 3-stage pipeline (counted vmcnt) ---------
// EPI 0: bf16 out;  EPI 1: fp32 out = res + v;  EPI 2: bf16 out = gelu(v)
template <int EPI, int BN>
__global__ __launch_bounds__(256) void gemm_bt(
    const ushort* __restrict__ A, const ushort* __restrict__ Bt,
    const float* __restrict__ bias, const float* __restrict__ res,
    ushort* __restrict__ outb, float* __restrict__ outf,
    int M, int N, int K, int gx)
{
  constexpr int NW = BN / 32;
  __shared__ __align__(16) ushort As[3][128 * 32];
  __shared__ __align__(16) ushort Bs[3][BN * 32];
  const int tid = threadIdx.x;
  const int lane = tid & 63;
  const int wv = tid >> 6;
  const int nwg = (int)gridDim.x;
  const int bid = (int)blockIdx.x;
  const int sw = (bid & 7) * (nwg >> 3) + (bid >> 3);
  const int rowBase = (sw / gx) * 128;
  const int colBase = (sw % gx) * BN;
  const int wr = (wv >> 1) * 64;
  const int wc = (wv & 1) * (BN / 2);

  f32x4 acc[4][NW] = {};

  const int e0 = tid * 8;
  const int r0 = e0 >> 5, c0 = e0 & 31;
  const int e1 = (tid + 256) * 8;
  const int r1 = e1 >> 5, c1 = e1 & 31;

  const ushort* Ag0 = A + (size_t)(rowBase + r0) * K + c0;
  const ushort* Ag1 = A + (size_t)(rowBase + r1) * K + c1;
  const ushort* Bg0 = Bt + (size_t)(colBase + r0) * K + c0;
  const ushort* Bg1 = Bt + (size_t)(colBase + r1) * K + c1;

  auto stage = [&](int buf, int k0) {
    async16(Ag0 + k0, &As[buf][e0]);
    async16(Ag1 + k0, &As[buf][e1]);
    async16(Bg0 + k0, &Bs[buf][e0]);
    if (BN == 128) async16(Bg1 + k0, &Bs[buf][e1]);
  };

  const int nt = K / 32;
  stage(0, 0);
  stage(1, 32);
  int b0 = 0, b1 = 1, b2 = 2;
  for (int t = 0; t < nt; ++t) {
    if (t < nt - 1) {
      if (BN == 128) asm volatile("s_waitcnt vmcnt(4)" ::: "memory");
      else           asm volatile("s_waitcnt vmcnt(3)" ::: "memory");
    } else {
      asm volatile("s_waitcnt vmcnt(0)" ::: "memory");
    }
    __builtin_amdgcn_sched_barrier(0);
    __builtin_amdgcn_s_barrier();
    __builtin_amdgcn_sched_barrier(0);
    if (t + 2 < nt) stage(b2, t * 32 + 64);

    bf16x8 af[4], bfr[NW];
#pragma unroll
    for (int m = 0; m < 4; ++m)
      af[m] = *(const bf16x8*)&As[b0][(wr + m * 16 + (lane & 15)) * 32 + (lane >> 4) * 8];
#pragma unroll
    for (int n = 0; n < NW; ++n)
      bfr[n] = *(const bf16x8*)&Bs[b0][(wc + n * 16 + (lane & 15)) * 32 + (lane >> 4) * 8];
#pragma unroll
    for (int m = 0; m < 4; ++m)
#pragma unroll
      for (int n = 0; n < NW; ++n)
        acc[m][n] = __builtin_amdgcn_mfma_f32_16x16x32_bf16(af[m], bfr[n], acc[m][n], 0, 0, 0);
    const int tmp = b0; b0 = b1; b1 = b2; b2 = tmp;
  }

#pragma unroll
  for (int n = 0; n < NW; ++n) {
    const int gc = colBase + wc + n * 16 + (lane & 15);
    const float bv = bias[gc];
#pragma unroll
    for (int m = 0; m < 4; ++m) {
#pragma unroll
      for (int j = 0; j < 4; ++j) {
        const int gr = rowBase + wr + m * 16 + (lane >> 4) * 4 + j;
        const float v = acc[m][n][j] + bv;
        if (EPI == 0) {
          outb[(size_t)gr * N + gc] = f2bf(v);
        } else if (EPI == 1) {
          outf[(size_t)gr * N + gc] = res[(size_t)gr * N + gc] + v;
        } else {
          const float g = 0.5f * v * (1.0f + erff(v * 0.70710678118654752f));
          outb[(size_t)gr * N + gc] = f2bf(g);
        }
      }
    }
  }
}

// ---------------- causal flash attention, 64x64 tiles, hd=64 -------------
// (round-9 structure + setprio, 60.7 us verified in round 15)
__global__ __launch_bounds__(256) void attn_kernel(
    const ushort* __restrict__ qkv, ushort* __restrict__ att)
{
  __shared__ __align__(16) ushort Ks[2][64 * 64];
  __shared__ __align__(16) ushort Vt[2][64 * 64];   // V^T [d][col: kh*32+sigma]

  const int tid = threadIdx.x;
  const int lane = tid & 63;
  const int wv = tid >> 6;
  const int g = lane >> 4;
  const int ql = lane & 15;
  const int kh = wv & 1;          // key-half owned
  const int qh = wv >> 1;         // q-half owned
  // snake remap: CU's resident blocks {p, 511-p, 512+p} -> balanced work
  const int p_ = blockIdx.x & 255, grp = blockIdx.x >> 8;
  const int item = (grp & 1) ? (grp * 256 + 255 - p_) : (grp * 256 + p_);
  const int qb = 63 - (item / 12);
  const int h = item % 12;
  const int t0 = qb * 64;
  const size_t rs = 3 * CDIM;
  const int qo = h * HD, ko = CDIM + h * HD, vo = 2 * CDIM + h * HD;

  const float cexp = 0.18033688f;            // 0.125 * log2(e)
  const float cbias = -32.0f * 0.18033688f;  // fixed max M_raw = 32

  // K staging: pre-swizzled global source -> linear LDS dest
  const int L0 = tid * 16, L1 = (tid + 256) * 16;
  const int r_0 = L0 >> 7, c_0 = ((L0 >> 4) & 7) ^ (r_0 & 7);
  const int r_1 = L1 >> 7, c_1 = ((L1 >> 4) & 7) ^ (r_1 & 7);
  const ushort* kg0 = qkv + (size_t)r_0 * rs + ko + c_0 * 8;
  const ushort* kg1 = qkv + (size_t)r_1 * rs + ko + c_1 * 8;

  // V reg staging: keys (vt, vt+1) x d in [vd, vd+8)
  const int vt = (tid >> 3) * 2;
  const int vd = (tid & 7) * 8;
  const int s32 = vt & 31;
  const int col2 = (vt >> 5) * 64 + (8 * ((s32 >> 2) & 3) + 4 * (s32 >> 4) + (s32 & 3)) * 2;
  const ushort* vg = qkv + (size_t)vt * rs + vo + vd;

  // Q fragments: q rows 32qh + 16qg + ql, d-chunks kk
  bf16x8 qf[2][2];
#pragma unroll
  for (int qg = 0; qg < 2; ++qg) {
    const ushort* qrow = qkv + (size_t)(t0 + 32 * qh + 16 * qg + ql) * rs + qo + g * 8;
    qf[qg][0] = *(const bf16x8*)(qrow);
    qf[qg][1] = *(const bf16x8*)(qrow + 32);
  }

  // prologue: vr(0), K(0) -> LDS, pack-write V^T(0)
  s16x8 vA0 = *(const s16x8*)(vg);
  s16x8 vA1 = *(const s16x8*)(vg + rs);
  async16(kg0, (char*)Ks[0] + L0);
  async16(kg1, (char*)Ks[0] + L1);
#pragma unroll
  for (int jj = 0; jj < 8; ++jj) {      // compiler waits vr(0) here
    const int d = vd + jj;
    const uint val = (uint)(ushort)vA0[jj] | ((uint)(ushort)vA1[jj] << 16);
    *(uint*)((char*)Vt[0] + d * 128 + (col2 ^ (((d >> 1) & 7) << 4))) = val;
  }

  f32x4 accO[2][4] = {};
  f32x4 accL[2] = {};
  const bf16x8 ones = __builtin_bit_cast(bf16x8,
      (u32x4){0x3F803F80u, 0x3F803F80u, 0x3F803F80u, 0x3F803F80u});
  const int swzv = (ql >> 1) & 7;

  int cur = 0;
  auto body = [&](int kb, int curb, auto diag_c) {
    constexpr bool DIAG = decltype(diag_c)::value;
    const size_t koff = (size_t)(kb + 1) * 64 * rs;

    // issue vr(kb+1) before the wait (stays in flight across this body)
    if (!DIAG) {
      vA0 = *(const s16x8*)(vg + koff);
      vA1 = *(const s16x8*)(vg + koff + rs);
      asm volatile("s_waitcnt vmcnt(2) lgkmcnt(0)" ::: "memory");
    } else {
      asm volatile("s_waitcnt vmcnt(0) lgkmcnt(0)" ::: "memory");
    }
    __builtin_amdgcn_sched_barrier(0);
    __builtin_amdgcn_s_barrier();
    __builtin_amdgcn_sched_barrier(0);

    // stage K(kb+1) post-barrier (other buffer; readers of it passed barrier)
    if (!DIAG) {
      async16(kg0 + koff, (char*)Ks[curb ^ 1] + L0);
      async16(kg1 + koff, (char*)Ks[curb ^ 1] + L1);
    }

    // QK^T: D[key][q]; A = K rows (wave's 32), B = Q (wave's 32 rows, regs)
    f32x4 accS[2][2] = {};   // [kg][qg]
    __builtin_amdgcn_s_setprio(1);
#pragma unroll
    for (int kg = 0; kg < 2; ++kg)
#pragma unroll
      for (int kk = 0; kk < 2; ++kk) {
        const bf16x8 A = frag_read(Ks[curb], 32 * kh + 16 * kg + ql, kk, lane);
#pragma unroll
        for (int qg = 0; qg < 2; ++qg)
          accS[kg][qg] = __builtin_amdgcn_mfma_f32_16x16x32_bf16(
              A, qf[qg][kk], accS[kg][qg], 0, 0, 0);
      }
    __builtin_amdgcn_s_setprio(0);

    // p = 2^(s*c + cbias); mask only on peeled diag tile; pack in-reg
    bf16x8 pa[2];
#pragma unroll
    for (int qg = 0; qg < 2; ++qg) {
      float e[2][4];
#pragma unroll
      for (int kg = 0; kg < 2; ++kg)
#pragma unroll
        for (int j = 0; j < 4; ++j) {
          float s = exp2_fast(fmaf(accS[kg][qg][j], cexp, cbias));
          if (DIAG && (32 * kh + 16 * kg + 4 * g + j) > (32 * qh + 16 * qg + ql)) s = 0.f;
          e[kg][j] = s;
        }
      const uint w0 = cvtpk(e[0][0], e[0][1]);
      const uint w1 = cvtpk(e[0][2], e[0][3]);
      const uint w2 = cvtpk(e[1][0], e[1][1]);
      const uint w3 = cvtpk(e[1][2], e[1][3]);
      pa[qg] = __builtin_bit_cast(bf16x8, (u32x4){w0, w1, w2, w3});
    }

    // PV: D[q][d]; A = pa, B = Vt rows (d), wave's 32-key column slice.
    __builtin_amdgcn_s_setprio(1);
#pragma unroll
    for (int n = 0; n < 4; ++n) {
      const int byte = (16 * n + ql) * 128 + ((kh * 64 + 16 * g) ^ (swzv << 4));
      const bf16x8 bv = *(const bf16x8*)((const char*)Vt[curb] + byte);
#pragma unroll
      for (int qg = 0; qg < 2; ++qg)
        accO[qg][n] = __builtin_amdgcn_mfma_f32_16x16x32_bf16(pa[qg], bv, accO[qg][n], 0, 0, 0);
    }
#pragma unroll
    for (int qg = 0; qg < 2; ++qg)
      accL[qg] = __builtin_amdgcn_mfma_f32_16x16x32_bf16(pa[qg], ones, accL[qg], 0, 0, 0);
    __builtin_amdgcn_s_setprio(0);

    // pack-write V^T(kb+1)
    if (!DIAG) {
#pragma unroll
      for (int jj = 0; jj < 8; ++jj) {
        const int d = vd + jj;
        const uint val = (uint)(ushort)vA0[jj] | ((uint)(ushort)vA1[jj] << 16);
        *(uint*)((char*)Vt[curb ^ 1] + d * 128 + (col2 ^ (((d >> 1) & 7) << 4))) = val;
      }
    }
  };

  for (int kb = 0; kb < qb; ++kb) {
    body(kb, cur, std::false_type{});
    cur ^= 1;
  }
  body(qb, cur, std::true_type{});

  // -------- merge kh partials (fixed-max => exactly additive) ------------
  __syncthreads();                       // all PV reads of Vt/Ks done
  float* mO = (float*)&Ks[0][0];         // [qh][qg][n][lane] f32x4 = 16KB
  float* mL = (float*)&Vt[0][0];         // [qh][qg][lane] f32x4 = 4KB
  if (kh == 1) {
#pragma unroll
    for (int qg = 0; qg < 2; ++qg) {
#pragma unroll
      for (int n = 0; n < 4; ++n)
        *(f32x4*)&mO[(((qh * 2 + qg) * 4 + n) * 64 + lane) * 4] = accO[qg][n];
      *(f32x4*)&mL[((qh * 2 + qg) * 64 + lane) * 4] = accL[qg];
    }
  }
  __syncthreads();
  if (kh == 0) {
#pragma unroll
    for (int qg = 0; qg < 2; ++qg) {
      const f32x4 ls = accL[qg] + *(const f32x4*)&mL[((qh * 2 + qg) * 64 + lane) * 4];
      f32x4 inv4;
#pragma unroll
      for (int jr = 0; jr < 4; ++jr) inv4[jr] = 1.0f / ls[jr];
#pragma unroll
      for (int n = 0; n < 4; ++n) {
        const f32x4 o = accO[qg][n] +
            *(const f32x4*)&mO[(((qh * 2 + qg) * 4 + n) * 64 + lane) * 4];
#pragma unroll
        for (int jr = 0; jr < 4; ++jr) {
          const int tq = t0 + 32 * qh + 16 * qg + 4 * g + jr;
          const int d = 16 * n + ql;
          att[(size_t)tq * CDIM + h * HD + d] = f2bf(o[jr] * inv4[jr]);
        }
      }
    }
  }
}

// -------------------------------------------------------------------------
extern "C" void kernel_launch(void* const* d_in, const int* in_sizes, int n_in,
                              void* d_out, int out_size, void* d_ws, size_t ws_size,
                              hipStream_t stream)
{
  const float* x      = (const float*)d_in[0];
  const float* ln1_w  = (const float*)d_in[1];
  const float* ln1_b  = (const float*)d_in[2];
  const float* W_attn = (const float*)d_in[3];
  const float* b_attn = (const float*)d_in[4];
  const float* W_proj = (const float*)d_in[5];
  const float* b_proj = (const float*)d_in[6];
  const float* ln2_w  = (const float*)d_in[7];
  const float* ln2_b  = (const float*)d_in[8];
  const float* W_fc   = (const float*)d_in[9];
  const float* b_fc   = (const float*)d_in[10];
  const float* W_fc2  = (const float*)d_in[11];
  const float* b_fc2  = (const float*)d_in[12];
  float* out = (float*)d_out;

  char* base = (char*)d_ws;
  size_t off = 0;
  auto alloc = [&](size_t bytes) -> void* {
    void* q = base + off;
    off = (off + bytes + 255) & ~(size_t)255;
    return q;
  };
  ushort* Wt_attn = (ushort*)alloc(768ull * 2304 * 2);
  ushort* Wt_proj = (ushort*)alloc(768ull * 768 * 2);
  ushort* Wt_fc   = (ushort*)alloc(768ull * 3072 * 2);
  ushort* Wt_fc2  = (ushort*)alloc(3072ull * 768 * 2);
  ushort* t_ln    = (ushort*)alloc(4096ull * 768 * 2);
  ushort* t_att   = (ushort*)alloc(4096ull * 768 * 2);
  float*  t_x1    = (float*) alloc(4096ull * 768 * 4);
  ushort* t_big   = (ushort*)alloc(4096ull * 3072 * 2);
  ushort* t_qkv = t_big;     // qkv row-major (2304 cols)
  ushort* t_h   = t_big;     // FC hidden (after attn done with qkv)

  prep_kernel<<<11008, 256, 0, stream>>>(
      W_attn, Wt_attn, W_proj, Wt_proj, W_fc, Wt_fc, W_fc2, Wt_fc2,
      x, ln1_w, ln1_b, t_ln);
  gemm_bt<0, 128><<<18 * 32, 256, 0, stream>>>(
      t_ln, Wt_attn, b_attn, nullptr, t_qkv, nullptr, 4096, 2304, 768, 18);
  attn_kernel<<<dim3(768), 256, 0, stream>>>(t_qkv, t_att);
  gemm_bt<1, 64><<<12 * 32, 256, 0, stream>>>(
      t_att, Wt_proj, b_proj, x, nullptr, t_x1, 4096, 768, 768, 12);
  ln_kernel<<<4096, 256, 0, stream>>>(t_x1, ln2_w, ln2_b, t_ln);
  gemm_bt<2, 128><<<24 * 32, 256, 0, stream>>>(
      t_ln, Wt_fc, b_fc, nullptr, t_h, nullptr, 4096, 3072, 768, 24);
  gemm_bt<1, 64><<<12 * 32, 256, 0, stream>>>(
      t_h, Wt_fc2, b_fc2, t_x1, nullptr, out, 4096, 768, 3072, 12);
}